// Round 1
// baseline (972.020 us; speedup 1.0000x reference)
//
#include <hip/hip_runtime.h>

#define BB 16384
#define GG 8192
#define DD 256

constexpr int BM = 128, BN = 128, BK = 32;
constexpr int GSPLIT = 4;
constexpr int GCHUNK = GG / GSPLIT;   // 2048

// ---------------- kernel 1: inverse norms of group_features ----------------
__global__ __launch_bounds__(256)
void invn_kernel(const float* __restrict__ gf, float* __restrict__ invn) {
    int g = blockIdx.x;
    int t = threadIdx.x;
    float v = gf[(size_t)g * DD + t];
    float ss = v * v;
    #pragma unroll
    for (int off = 32; off >= 1; off >>= 1) ss += __shfl_xor(ss, off);
    __shared__ float acc[4];
    int wave = t >> 6, lane = t & 63;
    if (lane == 0) acc[wave] = ss;
    __syncthreads();
    if (t == 0) {
        float tot = acc[0] + acc[1] + acc[2] + acc[3];
        invn[g] = 1.0f / fmaxf(sqrtf(tot), 1e-12f);
    }
}

// ---------------- kernel 2: fused matmul + argmax ----------------
// grid: (BB/BM) x GSPLIT, block 256 threads (16 tx x 16 ty), 8x8 micro-tile.
__global__ __launch_bounds__(256, 2)
void argmax_kernel(const float* __restrict__ x, const float* __restrict__ gf,
                   const float* __restrict__ invn,
                   unsigned long long* __restrict__ keys) {
    __shared__ float As[BK][BM];   // k-major
    __shared__ float Bs[BK][BN];

    const int tid = threadIdx.x;
    const int tx = tid & 15, ty = tid >> 4;
    const int m0 = blockIdx.x * BM;
    const int gbase = blockIdx.y * GCHUNK;

    float best[8];
    int bidx[8];
    #pragma unroll
    for (int i = 0; i < 8; ++i) { best[i] = -3.0e38f; bidx[i] = 0; }

    for (int gt = 0; gt < GCHUNK; gt += BN) {
        float acc[8][8];
        #pragma unroll
        for (int i = 0; i < 8; ++i)
            #pragma unroll
            for (int j = 0; j < 8; ++j) acc[i][j] = 0.0f;

        for (int k0 = 0; k0 < DD; k0 += BK) {
            __syncthreads();   // protect prior reads before overwrite
            // stage A,B tiles: 128 rows x 32 k each; 4 float4 per thread per matrix
            #pragma unroll
            for (int s = 0; s < 4; ++s) {
                int f  = s * 256 + tid;     // 0..1023 float4 slots
                int m  = f >> 3;            // 0..127
                int kq = (f & 7) << 2;      // 0,4,...,28
                float4 va = *reinterpret_cast<const float4*>(
                    x + (size_t)(m0 + m) * DD + k0 + kq);
                As[kq + 0][m] = va.x; As[kq + 1][m] = va.y;
                As[kq + 2][m] = va.z; As[kq + 3][m] = va.w;
                float4 vb = *reinterpret_cast<const float4*>(
                    gf + (size_t)(gbase + gt + m) * DD + k0 + kq);
                Bs[kq + 0][m] = vb.x; Bs[kq + 1][m] = vb.y;
                Bs[kq + 2][m] = vb.z; Bs[kq + 3][m] = vb.w;
            }
            __syncthreads();
            #pragma unroll
            for (int k = 0; k < BK; ++k) {
                float4 a0 = *reinterpret_cast<const float4*>(&As[k][ty * 8]);
                float4 a1 = *reinterpret_cast<const float4*>(&As[k][ty * 8 + 4]);
                float4 b0 = *reinterpret_cast<const float4*>(&Bs[k][tx * 8]);
                float4 b1 = *reinterpret_cast<const float4*>(&Bs[k][tx * 8 + 4]);
                float a[8] = {a0.x, a0.y, a0.z, a0.w, a1.x, a1.y, a1.z, a1.w};
                float b[8] = {b0.x, b0.y, b0.z, b0.w, b1.x, b1.y, b1.z, b1.w};
                #pragma unroll
                for (int i = 0; i < 8; ++i)
                    #pragma unroll
                    for (int j = 0; j < 8; ++j)
                        acc[i][j] = fmaf(a[i], b[j], acc[i][j]);
            }
        }

        // epilogue: scale by group inv-norm, update running argmax
        #pragma unroll
        for (int j = 0; j < 8; ++j) {
            int g = gbase + gt + tx * 8 + j;
            float s = invn[g];
            #pragma unroll
            for (int i = 0; i < 8; ++i) {
                float v = acc[i][j] * s;
                if (v > best[i]) { best[i] = v; bidx[i] = g; }   // strict >: first index wins
            }
        }
    }

    // reduce across the 16 tx-lanes sharing each row (consecutive lanes in-wave)
    #pragma unroll
    for (int i = 0; i < 8; ++i) {
        float v = best[i]; int gi = bidx[i];
        #pragma unroll
        for (int off = 1; off < 16; off <<= 1) {
            float ov = __shfl_xor(v, off);
            int   og = __shfl_xor(gi, off);
            if (ov > v || (ov == v && og < gi)) { v = ov; gi = og; }
        }
        if (tx == 0) {
            int row = m0 + ty * 8 + i;
            unsigned uv = __float_as_uint(v);
            uv = (uv & 0x80000000u) ? ~uv : (uv | 0x80000000u);   // order-preserving
            unsigned long long key =
                ((unsigned long long)uv << 32) | (unsigned)(GG - 1 - gi); // lower idx wins ties
            atomicMax(&keys[row], key);
        }
    }
}

// ---------------- kernel 3: scatter-add sums and counts ----------------
__global__ __launch_bounds__(256)
void accum_kernel(const float* __restrict__ x,
                  const unsigned long long* __restrict__ keys,
                  float* __restrict__ sums, float* __restrict__ counts) {
    int row = blockIdx.x;
    unsigned long long k = keys[row];
    int g = GG - 1 - (int)(unsigned)(k & 0xffffffffu);
    if (threadIdx.x == 0) atomicAdd(&counts[g], 1.0f);
    atomicAdd(&sums[(size_t)g * DD + threadIdx.x],
              x[(size_t)row * DD + threadIdx.x]);
}

// ---------------- kernel 4: EMA finalize ----------------
__global__ __launch_bounds__(256)
void final_kernel(const float* __restrict__ gf, const float* __restrict__ sums,
                  const float* __restrict__ counts, float* __restrict__ out) {
    int i = blockIdx.x * 256 + threadIdx.x;   // 0..GG*DD-1
    int g = i >> 8;
    float mean = sums[i] / fmaxf(counts[g], 1.0f);
    out[i] = 0.99f * gf[i] + 0.01f * mean;
}

extern "C" void kernel_launch(void* const* d_in, const int* in_sizes, int n_in,
                              void* d_out, int out_size, void* d_ws, size_t ws_size,
                              hipStream_t stream) {
    const float* x  = (const float*)d_in[0];   // [16384, 256]
    const float* gf = (const float*)d_in[1];   // [8192, 256]
    float* out = (float*)d_out;                // [8192, 256]

    char* ws = (char*)d_ws;
    float* invn   = (float*)ws;                                   // 32 KB
    float* sums   = (float*)(ws + 32 * 1024);                     // 8 MB
    float* counts = (float*)(ws + 32 * 1024 + 8 * 1024 * 1024);   // 32 KB
    unsigned long long* keys =
        (unsigned long long*)(ws + 64 * 1024 + 8 * 1024 * 1024);  // 128 KB

    // zero sums+counts (contiguous) and keys — ws is poisoned each launch
    hipMemsetAsync(sums, 0, 8 * 1024 * 1024 + 32 * 1024, stream);
    hipMemsetAsync(keys, 0, (size_t)BB * 8, stream);

    invn_kernel<<<GG, 256, 0, stream>>>(gf, invn);
    argmax_kernel<<<dim3(BB / BM, GSPLIT), 256, 0, stream>>>(x, gf, invn, keys);
    accum_kernel<<<BB, 256, 0, stream>>>(x, keys, sums, counts);
    final_kernel<<<GG * DD / 256, 256, 0, stream>>>(gf, sums, counts, out);
}

// Round 2
// 931.310 us; speedup vs baseline: 1.0437x; 1.0437x over previous
//
#include <hip/hip_runtime.h>

#define BB 16384
#define GG 8192
#define DD 256

typedef __attribute__((ext_vector_type(8))) short bf16x8;
typedef __attribute__((ext_vector_type(4))) float f32x4;
typedef unsigned int u32;
typedef unsigned long long u64;

__device__ __forceinline__ u32 enc_f32(float v) {
    u32 u = __float_as_uint(v);
    return (u & 0x80000000u) ? ~u : (u | 0x80000000u);
}
__device__ __forceinline__ float dec_f32(u32 e) {
    u32 u = (e & 0x80000000u) ? (e ^ 0x80000000u) : ~e;
    return __uint_as_float(u);
}

// async 16B global->LDS (wave-uniform LDS base + lane*16 implicit)
__device__ __forceinline__ void async_copy16(void* lds, const void* g) {
    __builtin_amdgcn_global_load_lds(
        (const __attribute__((address_space(1))) void*)g,
        (__attribute__((address_space(3))) void*)lds, 16, 0, 0);
}

// ---------------- prep: fp32 -> bf16 (RNE) + inverse norms ----------------
__global__ __launch_bounds__(256)
void prep_kernel(const float* __restrict__ src, unsigned short* __restrict__ dstb,
                 float* __restrict__ invn) {
    int r = blockIdx.x, t = threadIdx.x;
    float v = src[(size_t)r * DD + t];
    u32 u = __float_as_uint(v);
    u32 lsb = (u >> 16) & 1u;
    dstb[(size_t)r * DD + t] = (unsigned short)((u + 0x7fffu + lsb) >> 16); // RNE bf16
    float ss = v * v;
    #pragma unroll
    for (int off = 32; off >= 1; off >>= 1) ss += __shfl_xor(ss, off);
    __shared__ float acc[4];
    if ((t & 63) == 0) acc[t >> 6] = ss;
    __syncthreads();
    if (t == 0) {
        float tot = acc[0] + acc[1] + acc[2] + acc[3];
        invn[r] = 1.0f / fmaxf(sqrtf(tot), 1e-12f);
    }
}

// exact fp32 re-evaluation for a candidate (same seq order as round-1 kernel)
__device__ __attribute__((noinline))
void exact_update(int row, int col, const float* __restrict__ x,
                  const float* __restrict__ gf, const float* __restrict__ invg,
                  u64* __restrict__ keys) {
    const float4* xr = (const float4*)(x + (size_t)row * DD);
    const float4* gr = (const float4*)(gf + (size_t)col * DD);
    float s = 0.f;
    #pragma unroll 4
    for (int d = 0; d < DD / 4; ++d) {
        float4 a = xr[d], b = gr[d];
        s = fmaf(a.x, b.x, s); s = fmaf(a.y, b.y, s);
        s = fmaf(a.z, b.z, s); s = fmaf(a.w, b.w, s);
    }
    float ve = s * invg[col];   // invx omitted: positive row-constant, argmax-invariant
    u64 key = ((u64)enc_f32(ve) << 32) | (u32)(GG - 1 - col);
    atomicMax(keys + row, key);
}

// ---------------- bf16 MFMA GEMM, 128x128 tile, BK=32, 4 waves ----------------
template <int PASS>
__global__ __launch_bounds__(256, 2)
void gemm_pass(const unsigned short* __restrict__ xb,
               const unsigned short* __restrict__ gb,
               const float* __restrict__ invx, const float* __restrict__ invg,
               u32* __restrict__ amax,
               const float* __restrict__ x, const float* __restrict__ gf,
               u64* __restrict__ keys) {
    __shared__ unsigned short Ash[128 * 32];
    __shared__ unsigned short Bsh[128 * 32];

    const int tid  = threadIdx.x;
    const int lane = tid & 63;
    const int w    = tid >> 6;       // wave 0..3
    const int wr   = w >> 1, wc = w & 1;
    const int m0   = blockIdx.x * 128;
    const int g0   = blockIdx.y * 128;

    f32x4 acc[4][4];
    #pragma unroll
    for (int i = 0; i < 4; ++i)
        #pragma unroll
        for (int j = 0; j < 4; ++j) acc[i][j] = (f32x4){0.f, 0.f, 0.f, 0.f};

    const int srow  = lane >> 2;     // 0..15 (staging row within 16-row chunk)
    const int sslot = lane & 3;      // 16B slot within 64B row

    for (int k0 = 0; k0 < DD; k0 += 32) {
        __syncthreads();             // previous tile fully consumed
        #pragma unroll
        for (int q = 0; q < 2; ++q) {
            int rA = w * 32 + q * 16 + srow;             // LDS-local row 0..127
            const unsigned short* sA = xb + (size_t)(m0 + rA) * DD + k0 + sslot * 8;
            async_copy16(&Ash[(w * 32 + q * 16) * 32], sA);
            const unsigned short* sB = gb + (size_t)(g0 + rA) * DD + k0 + sslot * 8;
            async_copy16(&Bsh[(w * 32 + q * 16) * 32], sB);
        }
        __syncthreads();             // implicit vmcnt(0) drain before barrier

        const int fr = lane & 15;    // row (A) / col (B) within fragment
        const int sl = lane >> 4;    // k-slice 0..3 (8 bf16 each)
        bf16x8 af[4], bfr[4];
        #pragma unroll
        for (int i = 0; i < 4; ++i) {
            int r = wr * 64 + i * 16 + fr;
            af[i]  = *(const bf16x8*)&Ash[r * 32 + sl * 8];
            int c = wc * 64 + i * 16 + fr;
            bfr[i] = *(const bf16x8*)&Bsh[c * 32 + sl * 8];
        }
        #pragma unroll
        for (int i = 0; i < 4; ++i)
            #pragma unroll
            for (int j = 0; j < 4; ++j)
                acc[i][j] = __builtin_amdgcn_mfma_f32_16x16x32_bf16(
                    af[i], bfr[j], acc[i][j], 0, 0, 0);
    }

    // epilogue: C/D layout col = lane&15, row = (lane>>4)*4 + reg
    const int fr = lane & 15;
    const int fq = lane >> 4;
    if (PASS == 1) {
        #pragma unroll
        for (int i = 0; i < 4; ++i) {
            #pragma unroll
            for (int r = 0; r < 4; ++r) {
                int row = m0 + wr * 64 + i * 16 + fq * 4 + r;
                float vmax = -3.0e38f;
                #pragma unroll
                for (int j = 0; j < 4; ++j) {
                    int col = g0 + wc * 64 + j * 16 + fr;
                    vmax = fmaxf(vmax, acc[i][j][r] * invg[col]);
                }
                #pragma unroll
                for (int off = 1; off < 16; off <<= 1)
                    vmax = fmaxf(vmax, __shfl_xor(vmax, off));
                if (fr == 0) atomicMax(&amax[row], enc_f32(vmax * invx[row]));
            }
        }
    } else {
        #pragma unroll
        for (int i = 0; i < 4; ++i) {
            #pragma unroll
            for (int r = 0; r < 4; ++r) {
                int row = m0 + wr * 64 + i * 16 + fq * 4 + r;
                float thr = dec_f32(amax[row]) - 0.02f;   // eps >= 2B = 2^-7
                float ivx = invx[row];
                #pragma unroll
                for (int j = 0; j < 4; ++j) {
                    int col = g0 + wc * 64 + j * 16 + fr;
                    float v = acc[i][j][r] * invg[col] * ivx;
                    if (v >= thr) exact_update(row, col, x, gf, invg, keys);
                }
            }
        }
    }
}

// ---------------- scatter-add sums and counts ----------------
__global__ __launch_bounds__(256)
void accum_kernel(const float* __restrict__ x, const u64* __restrict__ keys,
                  float* __restrict__ sums, float* __restrict__ counts) {
    int row = blockIdx.x;
    u64 k = keys[row];
    int g = GG - 1 - (int)(u32)(k & 0xffffffffu);
    if (threadIdx.x == 0) atomicAdd(&counts[g], 1.0f);
    atomicAdd(&sums[(size_t)g * DD + threadIdx.x], x[(size_t)row * DD + threadIdx.x]);
}

// ---------------- EMA finalize ----------------
__global__ __launch_bounds__(256)
void final_kernel(const float* __restrict__ gf, const float* __restrict__ sums,
                  const float* __restrict__ counts, float* __restrict__ out) {
    int i = blockIdx.x * 256 + threadIdx.x;
    int g = i >> 8;
    float mean = sums[i] / fmaxf(counts[g], 1.0f);
    out[i] = 0.99f * gf[i] + 0.01f * mean;
}

extern "C" void kernel_launch(void* const* d_in, const int* in_sizes, int n_in,
                              void* d_out, int out_size, void* d_ws, size_t ws_size,
                              hipStream_t stream) {
    const float* x  = (const float*)d_in[0];   // [16384, 256]
    const float* gf = (const float*)d_in[1];   // [8192, 256]
    float* out = (float*)d_out;

    char* ws = (char*)d_ws;
    unsigned short* xb = (unsigned short*)ws;                       // 8 MB
    unsigned short* gb = (unsigned short*)(ws + 8388608);           // 4 MB
    float* invx   = (float*)(ws + 12582912);                        // 64 KB
    float* invg   = (float*)(ws + 12648448);                        // 32 KB
    u32*   amax   = (u32*)  (ws + 12681216);                        // 64 KB
    u64*   keys   = (u64*)  (ws + 12746752);                        // 128 KB
    float* counts = (float*)(ws + 12877824);                        // 32 KB
    float* sums   = (float*)ws;   // aliases xb (dead after pass 2); both 8 MB

    // zero amax+keys+counts (contiguous 224 KB)
    hipMemsetAsync(amax, 0, 229376, stream);

    prep_kernel<<<BB, 256, 0, stream>>>(x,  xb, invx);
    prep_kernel<<<GG, 256, 0, stream>>>(gf, gb, invg);

    dim3 grid(BB / 128, GG / 128);
    gemm_pass<1><<<grid, 256, 0, stream>>>(xb, gb, invx, invg, amax, x, gf, keys);
    gemm_pass<2><<<grid, 256, 0, stream>>>(xb, gb, invx, invg, amax, x, gf, keys);

    // sums reuses xb's region — zero it after pass 2 (stream-ordered)
    hipMemsetAsync(sums, 0, 8388608, stream);

    accum_kernel<<<BB, 256, 0, stream>>>(x, keys, sums, counts);
    final_kernel<<<GG * DD / 256, 256, 0, stream>>>(gf, sums, counts, out);
}